// Round 12
// baseline (143.366 us; speedup 1.0000x reference)
//
#include <hip/hip_runtime.h>
#include <stdint.h>

#define K_DIM 1024
#define N_DIM 1024
#define BM 256
#define BN 256
#define BK 32
#define NT (K_DIM / BK)             // 32 K-tiles
#define AOFF_U32 (BM * 16)          // A region: 256 rows x 16 u32
#define UNIT_U32 ((BM + BN) * 16)   // 32 KB per ring unit
// ring of 4 units = 128 KB

#define AS1 __attribute__((address_space(1)))
#define AS3 __attribute__((address_space(3)))

typedef __attribute__((ext_vector_type(4))) float f32x4;
typedef __attribute__((ext_vector_type(8))) short bf16x8;
typedef __attribute__((ext_vector_type(4))) uint32_t u32x4;

// round-half-up to bf16, pack two: low 16 = a, high 16 = b
__device__ __forceinline__ uint32_t pack_bf16(float a, float b) {
  uint32_t ua = __builtin_bit_cast(uint32_t, a) + 0x8000u;
  uint32_t ub = __builtin_bit_cast(uint32_t, b) + 0x8000u;
  return __builtin_amdgcn_perm(ub, ua, 0x07060302u);
}

__device__ __forceinline__ float wbin1(float v, float kkv, float aav) {
  float t = v * kkv;
  t = fminf(fmaxf(t, -1.0f), 1.0f);
  return t * aav;
}

// ---------------- kernel 1: w_bin = bf16(aa*clamp(kk*w,-1,1)) into ws ------
__global__ __launch_bounds__(256) void wconv(const float* __restrict__ w,
                                             const float* __restrict__ kkp,
                                             const float* __restrict__ aap,
                                             uint32_t* __restrict__ wb) {
  const float kkv = kkp[0];
  const float aav = aap[0];
  const int g = blockIdx.x * 256 + threadIdx.x;  // 16 floats per thread
  const f32x4* src = (const f32x4*)(w + (size_t)g * 16);
  f32x4 v0 = src[0], v1 = src[1], v2 = src[2], v3 = src[3];
  uint32_t p[8];
#pragma unroll
  for (int i = 0; i < 4; ++i) {
    f32x4 v = i == 0 ? v0 : (i == 1 ? v1 : (i == 2 ? v2 : v3));
    p[2 * i] = pack_bf16(wbin1(v[0], kkv, aav), wbin1(v[1], kkv, aav));
    p[2 * i + 1] = pack_bf16(wbin1(v[2], kkv, aav), wbin1(v[3], kkv, aav));
  }
  u32x4* dst = (u32x4*)(wb + (size_t)g * 8);
  dst[0] = u32x4{p[0], p[1], p[2], p[3]};
  dst[1] = u32x4{p[4], p[5], p[6], p[7]};
}

// ---------------- kernel 2: fused-A free-run 4-ring GEMM -------------------
// R10's exact winning structure (256x256 tile, 8 waves 2x4, wave 128x64,
// BK=32, 4-unit 128 KB ring, free-run body, 1 barrier/tile, counted vmcnt)
// with the fp32->bf16 A-conversion fused in:
//   tile t: issue A(t+3) fp32 loads (regs) + B(t+3) DMA;
//           mid-tile vmcnt(8) retires A(t+2) only -> pack + 2 ds_write_b128
//           into unit (t+2)&3 (its readers finished at barrier t-2);
//           boundary lgkmcnt(0) + barrier.  vmcnt never 0 until the tail.
// Per-wave vmem order/tile: A 4, B 2 -> entry outstanding 6 = A(t+2)+B(t+2);
// after issuing 6 more, vmcnt(8) retires exactly A(t+2). Tail: vmcnt(2) at
// t=NT-3 (no new issues), vmcnt(0) at t=NT-2.
// Two named A-reg sets, manual unroll-2 (parity (t+2)&1 = t&1; rule #20).
// Swizzle both sides: phys_slot = slot ^ ((row>>1)&3), row = 16 u32.
__global__ __launch_bounds__(512, 2) void binlin_fused4(
    const float* __restrict__ x, const uint32_t* __restrict__ wb,
    const float* __restrict__ bias, float* __restrict__ out) {
  __shared__ uint32_t lds[4 * UNIT_U32];  // 128 KB

  const int tid = threadIdx.x;

  // bijective XCD swizzle (grid=512): 4 n-blocks of an m-panel -> same L2
  const int per = gridDim.x >> 3;
  const int logical = (blockIdx.x & 7) * per + (blockIdx.x >> 3);
  const int mIdx = logical >> 2;  // N_DIM/BN = 4
  const int nIdx = logical & 3;
  const int row0 = mIdx * BM;
  const int col0 = nIdx * BN;

  const int w8 = tid >> 6;
  const int lane = tid & 63;

  // ---- A reg-staging: thread -> row r = tid>>1 (0..255), half h = tid&1
  // (16 consecutive floats of the 32-float K-slice) ----
  const int r = tid >> 1;
  const int h = tid & 1;
  const float* ga = x + (size_t)(row0 + r) * K_DIM + h * 16;
  const int sw = (r >> 1) & 3;
  const int awidx0 = r * 16 + (((h * 2) ^ sw) * 4);
  const int awidx1 = r * 16 + (((h * 2 + 1) ^ sw) * 4);

  // ---- B staging via global_load_lds (pre-swizzled source), 2 ops/wave ----
  const int rl = lane >> 2;
  const int sl = (lane & 3) ^ ((lane >> 3) & 3);
  const uint32_t* gb_base =
      wb + (size_t)(col0 + w8 * 32 + rl) * (K_DIM / 2) + sl * 4;

  // ---- compute indices (wave 128x64) ----
  const int wr = w8 >> 2;   // 0..1 (m half)
  const int wc = w8 & 3;    // 0..3 (n quarter)
  const int cl = lane & 15;
  const int kg = lane >> 4;

  f32x4 acc[8][4] = {};
  bf16x8 af[8], bfr[2][2];
  f32x4 XA0, XA1, XA2, XA3, XB0, XB1, XB2, XB3;  // two A-sets in flight

#define LOAD_A4(kt, R0, R1, R2, R3)                            \
  do {                                                         \
    const f32x4* pa = (const f32x4*)(ga + (size_t)(kt) * 32);  \
    R0 = pa[0]; R1 = pa[1]; R2 = pa[2]; R3 = pa[3];            \
  } while (0)

#define PACK_A(SD, R0, R1, R2, R3)                                       \
  do {                                                                   \
    u32x4 q0 = {pack_bf16(R0[0], R0[1]), pack_bf16(R0[2], R0[3]),        \
                pack_bf16(R1[0], R1[1]), pack_bf16(R1[2], R1[3])};       \
    u32x4 q1 = {pack_bf16(R2[0], R2[1]), pack_bf16(R2[2], R2[3]),        \
                pack_bf16(R3[0], R3[1]), pack_bf16(R3[2], R3[3])};       \
    *(u32x4*)((SD) + awidx0) = q0;                                       \
    *(u32x4*)((SD) + awidx1) = q1;                                       \
  } while (0)

#define STAGE_B1(kt, SD, c)                                              \
  __builtin_amdgcn_global_load_lds(                                      \
      (const AS1 uint32_t*)(gb_base + (size_t)((c)*16) * (K_DIM / 2) +   \
                            (kt)*16),                                    \
      (AS3 uint32_t*)((SD) + AOFF_U32 + (w8 * 32 + (c)*16) * 16), 16, 0, 0)

#define READ_AF(AB)                                                          \
  _Pragma("unroll") for (int m = 0; m < 8; ++m) {                            \
    int rr = wr * 128 + m * 16 + cl;                                         \
    af[m] =                                                                  \
        *(const bf16x8*)((AB) + rr * 16 + ((kg ^ ((rr >> 1) & 3)) * 4));     \
  }

#define READ_BF(BB, NH)                                                      \
  _Pragma("unroll") for (int n = 0; n < 2; ++n) {                            \
    int rr = wc * 64 + ((NH)*2 + n) * 16 + cl;                               \
    bfr[NH][n] =                                                             \
        *(const bf16x8*)((BB) + rr * 16 + ((kg ^ ((rr >> 1) & 3)) * 4));     \
  }

#define MFMA_CL(NH)                                                          \
  __builtin_amdgcn_s_setprio(1);                                             \
  _Pragma("unroll") for (int m = 0; m < 8; ++m)                              \
  _Pragma("unroll") for (int n = 0; n < 2; ++n)                              \
  acc[m][(NH)*2 + n] = __builtin_amdgcn_mfma_f32_16x16x32_bf16(              \
      af[m], bfr[NH][n], acc[m][(NH)*2 + n], 0, 0, 0);                       \
  __builtin_amdgcn_s_setprio(0);

#define TILE(T, PA0, PA1, PA2, PA3, PL0, PL1, PL2, PL3)                      \
  do {                                                                       \
    const int t_ = (T);                                                      \
    const uint32_t* AB = &lds[(t_ & 3) * UNIT_U32];                          \
    const uint32_t* BB = AB + AOFF_U32;                                      \
    uint32_t* SD3 = &lds[((t_ + 3) & 3) * UNIT_U32];                         \
    uint32_t* SD2 = &lds[((t_ + 2) & 3) * UNIT_U32];                         \
    const bool more3 = (t_ + 3) < NT;                                        \
    const bool more2 = (t_ + 2) < NT;                                        \
    if (more3) {                                                             \
      LOAD_A4(t_ + 3, PL0, PL1, PL2, PL3);                                   \
      STAGE_B1(t_ + 3, SD3, 0);                                              \
      STAGE_B1(t_ + 3, SD3, 1);                                              \
    }                                                                        \
    READ_AF(AB);                                                             \
    READ_BF(BB, 0);                                                          \
    MFMA_CL(0);                                                              \
    if (more2) {                                                             \
      if (more3) {                                                           \
        asm volatile("s_waitcnt vmcnt(8)" ::: "memory");                     \
      } else {                                                               \
        asm volatile("s_waitcnt vmcnt(2)" ::: "memory");                     \
      }                                                                      \
      PACK_A(SD2, PA0, PA1, PA2, PA3);                                       \
    }                                                                        \
    READ_BF(BB, 1);                                                          \
    MFMA_CL(1);                                                              \
    if (t_ == NT - 2) asm volatile("s_waitcnt vmcnt(0)" ::: "memory");       \
    if (t_ < NT - 1) {                                                       \
      asm volatile("s_waitcnt lgkmcnt(0)" ::: "memory");                     \
      __builtin_amdgcn_s_barrier();                                          \
    }                                                                        \
  } while (0)

  // ---- prologue: units 0,1 full; A(2) in XA regs; B(2) DMA in flight ----
  f32x4 A00, A01, A02, A03, A10, A11, A12, A13;
  LOAD_A4(0, A00, A01, A02, A03);
  STAGE_B1(0, &lds[0], 0);
  STAGE_B1(0, &lds[0], 1);
  LOAD_A4(1, A10, A11, A12, A13);
  STAGE_B1(1, &lds[UNIT_U32], 0);
  STAGE_B1(1, &lds[UNIT_U32], 1);
  LOAD_A4(2, XA0, XA1, XA2, XA3);
  STAGE_B1(2, &lds[2 * UNIT_U32], 0);
  STAGE_B1(2, &lds[2 * UNIT_U32], 1);
  PACK_A(&lds[0], A00, A01, A02, A03);            // auto-waits A(0)
  PACK_A(&lds[UNIT_U32], A10, A11, A12, A13);     // auto-waits A(1), B(0)
  asm volatile("s_waitcnt vmcnt(6)" ::: "memory");  // retire B(1); keep A2+B2
  asm volatile("s_waitcnt lgkmcnt(0)" ::: "memory");
  __builtin_amdgcn_s_barrier();

  // ---- main loop, manual unroll-2 for A-set parity ----
  for (int t2 = 0; t2 < NT; t2 += 2) {
    TILE(t2, XA0, XA1, XA2, XA3, XB0, XB1, XB2, XB3);
    TILE(t2 + 1, XB0, XB1, XB2, XB3, XA0, XA1, XA2, XA3);
  }

  // ---- epilogue: bias + fp32 store ----
#pragma unroll
  for (int n = 0; n < 4; ++n) {
    int col = col0 + wc * 64 + n * 16 + cl;
    float bv = bias[col];
#pragma unroll
    for (int m = 0; m < 8; ++m) {
      int rowb = row0 + wr * 128 + m * 16 + kg * 4;
#pragma unroll
      for (int i = 0; i < 4; ++i) {
        out[(size_t)(rowb + i) * N_DIM + col] = acc[m][n][i] + bv;
      }
    }
  }
#undef LOAD_A4
#undef PACK_A
#undef STAGE_B1
#undef READ_AF
#undef READ_BF
#undef MFMA_CL
#undef TILE
}

extern "C" void kernel_launch(void* const* d_in, const int* in_sizes, int n_in,
                              void* d_out, int out_size, void* d_ws, size_t ws_size,
                              hipStream_t stream) {
  const float* x = (const float*)d_in[0];
  const float* w = (const float*)d_in[1];
  const float* bias = (const float*)d_in[2];
  const float* kk = (const float*)d_in[3];
  const float* aa = (const float*)d_in[4];
  float* out = (float*)d_out;

  uint32_t* wb = (uint32_t*)d_ws;  // 2 MB bf16 w_bin
  wconv<<<(N_DIM * K_DIM) / (256 * 16), 256, 0, stream>>>(w, kk, aa, wb);

  const int M = in_sizes[0] / K_DIM;         // 32768
  const int grid = (M / BM) * (N_DIM / BN);  // 128 * 4 = 512
  binlin_fused4<<<grid, 512, 0, stream>>>(x, wb, bias, out);
}